// Round 1
// baseline (45.111 us; speedup 1.0000x reference)
//
#include <hip/hip_runtime.h>

// PositionBias: out[b,d1,d2,k] = x[b,d1,d2,k] + bias[min(|s_b - d1 + d2|, 127), k]
// s_b = crop_x[b,0] - crop_y[b,0]
// x: (8,256,256,64) f32, bias: (128,64) f32, out: same as x.
// Memory-bound: 268 MB total traffic, floor ~42.6 us @ 6.3 TB/s.

#define BIAS_SIZE 128
#define NUM_BINS 64
#define BB 8
#define CX 256
#define CY 256

__global__ __launch_bounds__(256) void PositionBias_26637387170463_kernel(
    const float4* __restrict__ x,
    const int* __restrict__ crop_x,
    const int* __restrict__ crop_y,
    const float4* __restrict__ bias,
    float4* __restrict__ out)
{
    // One block per (b, d1) row: 256 positions (d2) x 64 bins = 4096 float4s.
    const int row = blockIdx.x;           // row = b*CX + d1, 0..2047
    const int b_i = row >> 8;
    const int p   = row & 255;            // d1
    const int s   = crop_x[b_i * 2] - crop_y[b_i * 2];
    const int base = row * (CY * NUM_BINS / 4);   // float4 offset of this row (= row*4096)
    const int t = threadIdx.x;

    #pragma unroll
    for (int it = 0; it < 16; ++it) {
        int i  = t + it * 256;            // float4 index within the row, 0..4095
        int q  = i >> 4;                  // d2 (16 float4 per position)
        int k4 = i & 15;                  // which float4 of the 64-bin bias row
        int d  = s - p + q;
        int idx = abs(d);
        idx = idx < (BIAS_SIZE - 1) ? idx : (BIAS_SIZE - 1);

        float4 xv = x[base + i];
        float4 bv = bias[idx * (NUM_BINS / 4) + k4];
        float4 o;
        o.x = xv.x + bv.x;
        o.y = xv.y + bv.y;
        o.z = xv.z + bv.z;
        o.w = xv.w + bv.w;
        out[base + i] = o;
    }
}

extern "C" void kernel_launch(void* const* d_in, const int* in_sizes, int n_in,
                              void* d_out, int out_size, void* d_ws, size_t ws_size,
                              hipStream_t stream) {
    const float4* x      = (const float4*)d_in[0];
    const int*    crop_x = (const int*)d_in[1];
    const int*    crop_y = (const int*)d_in[2];
    const float4* bias   = (const float4*)d_in[3];
    float4*       out    = (float4*)d_out;

    dim3 grid(BB * CX);   // 2048 blocks, one per (b, d1) row
    dim3 block(256);
    PositionBias_26637387170463_kernel<<<grid, block, 0, stream>>>(
        x, crop_x, crop_y, bias, out);
}

// Round 3
// 44.475 us; speedup vs baseline: 1.0143x; 1.0143x over previous
//
#include <hip/hip_runtime.h>

// PositionBias: out[b,d1,d2,k] = x[b,d1,d2,k] + bias[min(|s_b - d1 + d2|, 127), k]
// s_b = crop_x[b,0] - crop_y[b,0]
// x: (8,256,256,64) f32, bias: (128,64) f32, out: same as x.
// Memory-bound. R1: 45.1 us, FETCH=65.7MB (half of x L3-resident), WRITE=134MB.
// R2: nt-stores for out (keep L3 for x) + batched loads for MLP.
// R3: fix compile — use native ext_vector float4 for the nontemporal builtin.

#define BIAS_SIZE 128
#define NUM_BINS 64
#define BB 8
#define CX 256
#define CY 256

typedef float f32x4 __attribute__((ext_vector_type(4)));

__global__ __launch_bounds__(256) void PositionBias_26637387170463_kernel(
    const f32x4* __restrict__ x,
    const int* __restrict__ crop_x,
    const int* __restrict__ crop_y,
    const f32x4* __restrict__ bias,
    f32x4* __restrict__ out)
{
    // One block per (b, d1) row: 256 positions (d2) x 16 float4/pos = 4096 float4s.
    const int row = blockIdx.x;           // row = b*CX + d1, 0..2047
    const int b_i = row >> 8;
    const int p   = row & 255;            // d1
    const int s   = crop_x[b_i * 2] - crop_y[b_i * 2];
    const int base = row * (CY * NUM_BINS / 4);   // float4 offset of this row
    const int t = threadIdx.x;
    const int sp = s - p;                 // idx = clamp(|sp + q|, 127)

    #pragma unroll
    for (int it = 0; it < 4; ++it) {
        f32x4 xv[4];
        f32x4 bv[4];
        int ii[4];
        // Phase 1: issue 8 loads (4 x + 4 bias) before any use -> deep MLP.
        #pragma unroll
        for (int j = 0; j < 4; ++j) {
            int i  = t + (it * 4 + j) * 256;   // float4 index within row
            ii[j]  = i;
            int q  = i >> 4;                   // d2
            int k4 = i & 15;                   // float4 within bias row
            int d  = sp + q;
            int idx = d < 0 ? -d : d;
            idx = idx < (BIAS_SIZE - 1) ? idx : (BIAS_SIZE - 1);
            xv[j] = x[base + i];
            bv[j] = bias[idx * (NUM_BINS / 4) + k4];
        }
        // Phase 2: add + non-temporal store (out never re-read -> don't cache).
        #pragma unroll
        for (int j = 0; j < 4; ++j) {
            f32x4 o = xv[j] + bv[j];
            __builtin_nontemporal_store(o, &out[base + ii[j]]);
        }
    }
}

extern "C" void kernel_launch(void* const* d_in, const int* in_sizes, int n_in,
                              void* d_out, int out_size, void* d_ws, size_t ws_size,
                              hipStream_t stream) {
    const f32x4* x      = (const f32x4*)d_in[0];
    const int*   crop_x = (const int*)d_in[1];
    const int*   crop_y = (const int*)d_in[2];
    const f32x4* bias   = (const f32x4*)d_in[3];
    f32x4*       out    = (f32x4*)d_out;

    dim3 grid(BB * CX);   // 2048 blocks, one per (b, d1) row
    dim3 block(256);
    PositionBias_26637387170463_kernel<<<grid, block, 0, stream>>>(
        x, crop_x, crop_y, bias, out);
}